// Round 9
// baseline (340.347 us; speedup 1.0000x reference)
//
#include <hip/hip_runtime.h>
#include <hip/hip_bf16.h>
#include <math.h>

#define B_     128
#define DIM_   512
#define HEADS_ 8
#define HD_    64
#define N_     196
#define NP_    224            // padded n (14 tiles of 16)
#define NROW_  208            // padded n rows (13 tiles of 16) for EB
#define SCALE_ 0.125f
#define BSTRIDE (DIM_ * N_)
#define J_     (B_ * NP_)     // 28672 GEMM columns (b*224+n)

typedef unsigned short u16;
typedef unsigned int   u32;
typedef __attribute__((ext_vector_type(8))) short bf16x8;   // 8 bf16 = 4 VGPRs
typedef __attribute__((ext_vector_type(4))) float f32x4;

__device__ __forceinline__ u16 f2bf(float f) {              // RNE fp32->bf16
    u32 u = __float_as_uint(f);
    return (u16)((u + 0x7fffu + ((u >> 16) & 1u)) >> 16);
}

// ---------------------------------------------------------------------------
// Frag-major layout (r11, verified): FM[row/16][k/32][quad][m16][8 bf16].
// u16 addr(row,k) = (row>>4)*8192 + (k>>5)*512 + ((k>>3)&3)*128 + (row&15)*8
//                 + (k&7)        [K=512 fixed -> 16 kt slots]
// One MFMA fragment (16 rows x 8 k for 64 lanes) = 1 KB CONTIGUOUS.
// A j-tile (128 rows x K=512) = 8 frag-rows = 128 KB CONTIGUOUS.
// ---------------------------------------------------------------------------

// fp32 weights -> frag-major bf16. dst chunk index == thread index (layout
// decode t = mb*1024 + kb*64 + q*16 + m16 equals addr/8). y=0: qkv, y=1: proj.
__global__ __launch_bounds__(256) void cvt_w2(
    const float* __restrict__ qw, u16* __restrict__ qd,
    const float* __restrict__ pw, u16* __restrict__ pd)
{
    const float* src = blockIdx.y ? pw : qw;
    u16* dst = blockIdx.y ? pd : qd;
    const int nch = blockIdx.y ? (DIM_ * DIM_ / 8) : (3 * DIM_ * DIM_ / 8);
    const int t = blockIdx.x * 256 + threadIdx.x;
    if (t < nch) {
        const int m16 = t & 15, q = (t >> 4) & 3, kb = (t >> 6) & 15, mb = t >> 10;
        const float* s = src + (size_t)(mb * 16 + m16) * DIM_ + kb * 32 + q * 8;
        const float4 v0 = reinterpret_cast<const float4*>(s)[0];
        const float4 v1 = reinterpret_cast<const float4*>(s)[1];
        uint4 o;
        o.x = (u32)f2bf(v0.x) | ((u32)f2bf(v0.y) << 16);
        o.y = (u32)f2bf(v0.z) | ((u32)f2bf(v0.w) << 16);
        o.z = (u32)f2bf(v1.x) | ((u32)f2bf(v1.y) << 16);
        o.w = (u32)f2bf(v1.z) | ((u32)f2bf(v1.w) << 16);
        reinterpret_cast<uint4*>(dst)[t] = o;
    }
}

// ---------------------------------------------------------------------------
// x fp32 [b][512][196] -> XT2 frag-major bf16 over rows j=b*224+n (pad rows
// unwritten garbage, masked downstream: EB=0 for m>=196, OT/out guarded).
// ---------------------------------------------------------------------------
__global__ __launch_bounds__(256) void cvt_xT(
    const float* __restrict__ x, u16* __restrict__ XT)
{
    __shared__ float tile[64][65];
    const int t = threadIdx.x;
    const int jj = t & 63, ii = t >> 6;
    const int ct = blockIdx.x, ntb = blockIdx.y, b = blockIdx.z;
    const float* xb = x + ((size_t)b * DIM_ + ct * 64) * N_;
    const int n0 = ntb * 64;
    #pragma unroll
    for (int s = 0; s < 16; ++s) {
        const int i = ii + s * 4;
        const int n = n0 + jj;
        tile[i][jj] = (n < N_) ? xb[(size_t)i * N_ + n] : 0.f;
    }
    __syncthreads();
    const int lo = t & 15, hi = t >> 4;
    const int c8 = hi & 7, ng = hi >> 3;
    #pragma unroll
    for (int s = 0; s < 2; ++s) {
        const int n_loc = (s * 2 + ng) * 16 + lo;
        const int nn = n0 + n_loc;
        if (nn < N_) {
            const int j = b * NP_ + nn;                 // NP_,n0 mult of 16 -> j&15==lo
            const int c0 = ct * 64 + c8 * 8;
            u16 vv[8];
            #pragma unroll
            for (int e = 0; e < 8; ++e) vv[e] = f2bf(tile[c8 * 8 + e][n_loc]);
            uint4 o;
            o.x = (u32)vv[0] | ((u32)vv[1] << 16);
            o.y = (u32)vv[2] | ((u32)vv[3] << 16);
            o.z = (u32)vv[4] | ((u32)vv[5] << 16);
            o.w = (u32)vv[6] | ((u32)vv[7] << 16);
            *reinterpret_cast<uint4*>(XT + (size_t)(j >> 4) * 8192
                + (c0 >> 5) * 512 + ((c0 >> 3) & 3) * 128 + (j & 15) * 8) = o;
        }
    }
}

// ---------------------------------------------------------------------------
// EB[h][208][224] = exp(bias[h][bidx[n][m]]) for n,m<196 else 0.
// ---------------------------------------------------------------------------
__global__ __launch_bounds__(256) void mk_eb(
    const float* __restrict__ biases, const int* __restrict__ bidx,
    float* __restrict__ EB)
{
    const int n = blockIdx.x, h = blockIdx.y;
    const int m = threadIdx.x;
    if (m < NP_) {
        float v = 0.f;
        if (n < N_ && m < N_) v = __expf(biases[h * N_ + bidx[n * N_ + m]]);
        EB[((size_t)h * NROW_ + n) * NP_ + m] = v;
    }
}

// ---------------------------------------------------------------------------
// r14: j-tile-resident GEMM, mt loop INSIDE. Why: r8/r9/r11/r12 (2-phase LDS,
// counted-vmcnt, register-direct, reg-dbuf) all pinned at 78-105us, MfmaUtil
// ~20% -- every one re-moves the XT panel per (mt,jt) block and pays per-
// block stage/prologue latency 12x. Now: ONE block per 128-col j-tile (224
// blocks, 512 thr / 8 waves). Stage the tile's FULL K panel (frag-major ->
// contiguous 128 KB) into LDS once (16 gload_lds rounds + ONE barrier), then
// loop all MT m-tiles with ZERO barriers: per kt, 8 A-frags register-direct
// from frag-major W (1.5 MB, L2-resident, shared by all blocks) + 4 B-frags
// ds_read_b128 from LDS (frag-major = contiguous 1 KB -> conflict-free, no
// swizzle) + 32 MFMA. XT read from HBM exactly ONCE (min possible); barrier
// count 16 -> 1; kt x mi body is straight-line code the scheduler pipelines
// freely; MFMA:load = 32:12/kt. Wave decomp: wx=wave&1 (64-col half),
// mtp=wave>>1 -> per mt each wave computes 128x64 (8x4 frags, 128 AGPR acc).
// Floors: MFMA 24.8us, LDS-read 7.7us, A-path 3 MB/block L1/L2.
// Epilogue = r11-verified code per 64-row group g (mbase=mt*128+g*64 ->
// part/h wave-uniform per group); acc row index g*4+fi.
// Epilogue QKV: qT/kT[b][h][n<=224][64] (8B stores), vS[b][h][d][224];
// pads stored unguarded -- EB=0 masks every pad contribution downstream.
// Epilogue proj: fp32 out[b][512][196], n guarded.
// ---------------------------------------------------------------------------
template<int MT>
__global__ __launch_bounds__(512) void gemmJ(
    const u16* __restrict__ Bt, const u16* __restrict__ W,
    const float* __restrict__ bias,
    u16* __restrict__ o_q, u16* __restrict__ o_k, u16* __restrict__ o_v,
    float* __restrict__ o_f)
{
    __shared__ u16 Bs[8 * 8192];        // 128 KB: j-tile frag-major K panel
    const int t = threadIdx.x;
    const int wave = t >> 6, lane = t & 63;
    const int m16 = lane & 15, quad = lane >> 4;
    const int jt = blockIdx.x;
    const int wx = wave & 1, mtp = wave >> 1;   // col half / mt parity (0..3)
    const int j0 = jt * 128;

    // ---- stage j-tile: 8192 x 16B chunks, contiguous src AND dst ----
    {
        const u16* src = Bt + (size_t)jt * 65536;
        #pragma unroll
        for (int i = 0; i < 16; ++i) {
            const int c = i * 512 + t;   // = i*512 + wave*64 + lane: dst is
                                         // wave-uniform base + lane*16 B
            __builtin_amdgcn_global_load_lds(
                (const __attribute__((address_space(1))) void*)(src + c * 8),
                (__attribute__((address_space(3))) void*)(Bs + c * 8), 16, 0, 0);
        }
    }
    __syncthreads();                     // single barrier; Bs read-only after

    const u16* Wb = W + quad * 128 + m16 * 8;
    const u16* Bw = Bs + (size_t)(wx * 4) * 8192 + quad * 128 + m16 * 8;
    const f32x4 z4 = {0.f, 0.f, 0.f, 0.f};

    for (int mi = 0; mi < MT / 4; ++mi) {
        const int mt = mi * 4 + mtp;

        f32x4 acc[8][4];
        #pragma unroll
        for (int fi = 0; fi < 8; ++fi)
            #pragma unroll
            for (int fj = 0; fj < 4; ++fj) acc[fi][fj] = z4;

        const u16* Am = Wb + (size_t)(mt * 8) * 8192;
        #pragma unroll
        for (int kt = 0; kt < 16; ++kt) {
            bf16x8 af[8], bf[4];
            #pragma unroll
            for (int fi = 0; fi < 8; ++fi)
                af[fi] = *reinterpret_cast<const bf16x8*>(Am + (size_t)fi * 8192 + kt * 512);
            #pragma unroll
            for (int fj = 0; fj < 4; ++fj)
                bf[fj] = *reinterpret_cast<const bf16x8*>(Bw + (size_t)fj * 8192 + kt * 512);
            #pragma unroll
            for (int fi = 0; fi < 8; ++fi)
                #pragma unroll
                for (int fj = 0; fj < 4; ++fj)
                    acc[fi][fj] = __builtin_amdgcn_mfma_f32_16x16x32_bf16(af[fi], bf[fj], acc[fi][fj], 0, 0, 0);
        }

        // ---- epilogue: two 64-row groups (r11-verified math per group) ----
        #pragma unroll
        for (int g = 0; g < 2; ++g) {
            const int mbase = mt * 128 + g * 64;     // 64-aligned -> part,h uniform
            float bb[4][4];
            #pragma unroll
            for (int fi = 0; fi < 4; ++fi)
                #pragma unroll
                for (int r = 0; r < 4; ++r) bb[fi][r] = bias[mbase + fi * 16 + quad * 4 + r];

            if (MT == 12) {
                const int part = mbase >> 9;         // 0=q 1=k 2=v
                const int h = (mbase & 511) >> 6;
                #pragma unroll
                for (int fj = 0; fj < 4; ++fj) {
                    const int j = j0 + wx * 64 + fj * 16 + m16;
                    const u32 b = (u32)j / 224u;
                    const int n = j - (int)b * 224;
                    if (part < 2) {                  // q,k -> [b][h][n][64], 8B packed
                        u16* base = (part == 0 ? o_q : o_k) + (((size_t)b * HEADS_ + h) * NP_ + n) * HD_;
                        #pragma unroll
                        for (int fi = 0; fi < 4; ++fi) {
                            const int d0 = fi * 16 + quad * 4;
                            uint2 pk;
                            pk.x = (u32)f2bf(acc[g * 4 + fi][fj][0] + bb[fi][0]) | ((u32)f2bf(acc[g * 4 + fi][fj][1] + bb[fi][1]) << 16);
                            pk.y = (u32)f2bf(acc[g * 4 + fi][fj][2] + bb[fi][2]) | ((u32)f2bf(acc[g * 4 + fi][fj][3] + bb[fi][3]) << 16);
                            *reinterpret_cast<uint2*>(base + d0) = pk;
                        }
                    } else {                         // v -> [b][h][d][224], 2B stores
                        u16* vb = o_v + (((size_t)b * HEADS_ + h) * HD_) * NP_ + n;
                        #pragma unroll
                        for (int fi = 0; fi < 4; ++fi) {
                            const int d0 = fi * 16 + quad * 4;
                            #pragma unroll
                            for (int r = 0; r < 4; ++r)
                                vb[(size_t)(d0 + r) * NP_] = f2bf(acc[g * 4 + fi][fj][r] + bb[fi][r]);
                        }
                    }
                }
            } else {                                 // proj: fp32 out[b][512][196]
                #pragma unroll
                for (int fj = 0; fj < 4; ++fj) {
                    const int j = j0 + wx * 64 + fj * 16 + m16;
                    const u32 b = (u32)j / 224u;
                    const int n = j - (int)b * 224;
                    if (n < N_) {
                        float* ob = o_f + (size_t)b * BSTRIDE + n;
                        #pragma unroll
                        for (int fi = 0; fi < 4; ++fi) {
                            const int r0 = mbase + fi * 16 + quad * 4;
                            #pragma unroll
                            for (int r = 0; r < 4; ++r)
                                ob[(size_t)(r0 + r) * N_] = acc[g * 4 + fi][fj][r] + bb[fi][r];
                        }
                    }
                }
            }
        }
    }
}

// ---------------------------------------------------------------------------
// MFMA attention per (b,h), 8 waves (512 thr). K and V staged in LDS once
// per block (verified r6 structure; r11: OT store frag-major, verified).
//   Ks[224][64] u16, chunk-XOR swizzled; Vs[64][232] row-padded;
//   P[8][16*232] per-wave. LDS 117.8 KB -> 1 block/CU.
// mx over all 14 mtiles incl. pads, EB=0 masks pad m; OT stores guarded n<196.
// ---------------------------------------------------------------------------
__global__ __launch_bounds__(512) void attn_mfma(
    const u16* __restrict__ qT, const u16* __restrict__ kT,
    const u16* __restrict__ vS, const float* __restrict__ EB,
    u16* __restrict__ OT)
{
    __shared__ u16 Ks[224 * 64];        // 28.7 KB, chunk-XOR swizzled
    __shared__ u16 Vs[64 * 232];        // 29.7 KB, row-padded
    __shared__ u16 P[8][16 * 232];      // 59.4 KB
    const int t = threadIdx.x;
    const int wave = t >> 6, lane = t & 63;
    const int m16 = lane & 15, quad = lane >> 4;
    const int b = blockIdx.x, h = blockIdx.y;
    const u16* qTb = qT + ((size_t)b * HEADS_ + h) * (NP_ * HD_);
    const u16* kTb = kT + ((size_t)b * HEADS_ + h) * (NP_ * HD_);
    const u16* vb  = vS + ((size_t)b * HEADS_ + h) * (HD_ * NP_);
    const float* ebh = EB + (size_t)h * NROW_ * NP_;
    u16* Pw = P[wave];
    const f32x4 z4 = {0.f, 0.f, 0.f, 0.f};

    // ---- stage K: 224 rows x 8 chunks(16B) = 1792 chunks over 512 thr ----
    #pragma unroll
    for (int i = 0; i < 4; ++i) {
        const int c = t + i * 512;
        if (c < 1792) {
            const int row = c >> 3, ch = c & 7;
            const bf16x8 d = *reinterpret_cast<const bf16x8*>(kTb + row * HD_ + ch * 8);
            *reinterpret_cast<bf16x8*>(Ks + row * 64 + ((ch ^ (row & 7)) * 8)) = d;
        }
    }
    // ---- stage V: 64 rows x 28 chunks(16B) = 1792 chunks, repack to 232 ----
    #pragma unroll
    for (int i = 0; i < 4; ++i) {
        const int c = t + i * 512;
        if (c < 1792) {
            const u32 row = (u32)c / 28u;
            const int ch = c - (int)row * 28;
            const bf16x8 d = *reinterpret_cast<const bf16x8*>(vb + (size_t)row * NP_ + ch * 8);
            *reinterpret_cast<bf16x8*>(Vs + row * 232 + ch * 8) = d;
        }
    }
    __syncthreads();

    for (int nt = wave; nt < 13; nt += 8) {
        f32x4 s[14];
        #pragma unroll
        for (int mt = 0; mt < 14; ++mt) s[mt] = z4;
        #pragma unroll
        for (int ks = 0; ks < 2; ++ks) {
            const bf16x8 a = *reinterpret_cast<const bf16x8*>(
                qTb + (size_t)(nt * 16 + m16) * HD_ + ks * 32 + quad * 8);
            const int ch = ((ks * 4 + quad) ^ (m16 & 7)) * 8;   // K swizzle inverse
            #pragma unroll
            for (int mtile = 0; mtile < 14; ++mtile) {
                const bf16x8 bf = *reinterpret_cast<const bf16x8*>(
                    Ks + (mtile * 16 + m16) * 64 + ch);
                s[mtile] = __builtin_amdgcn_mfma_f32_16x16x32_bf16(a, bf, s[mtile], 0, 0, 0);
            }
        }
        float mx[4] = {-INFINITY, -INFINITY, -INFINITY, -INFINITY};
        #pragma unroll
        for (int mt = 0; mt < 14; ++mt)
            #pragma unroll
            for (int r = 0; r < 4; ++r) mx[r] = fmaxf(mx[r], s[mt][r]);
        #pragma unroll
        for (int off = 1; off < 16; off <<= 1)
            #pragma unroll
            for (int r = 0; r < 4; ++r) mx[r] = fmaxf(mx[r], __shfl_xor(mx[r], off, 64));
        #pragma unroll
        for (int r = 0; r < 4; ++r) mx[r] *= SCALE_;

        const float* ebn = ebh + (size_t)(nt * 16 + quad * 4) * NP_ + m16;
        float sum[4] = {0.f, 0.f, 0.f, 0.f};
        #pragma unroll
        for (int mt = 0; mt < 14; ++mt) {
            #pragma unroll
            for (int r = 0; r < 4; ++r) {
                const float e = __expf(fmaf(s[mt][r], SCALE_, -mx[r])) * ebn[(size_t)r * NP_ + mt * 16];
                s[mt][r] = e;
                sum[r] += e;
            }
        }
        #pragma unroll
        for (int off = 1; off < 16; off <<= 1)
            #pragma unroll
            for (int r = 0; r < 4; ++r) sum[r] += __shfl_xor(sum[r], off, 64);
        float inv[4];
        #pragma unroll
        for (int r = 0; r < 4; ++r) inv[r] = 1.f / sum[r];

        #pragma unroll
        for (int mt = 0; mt < 14; ++mt)
            #pragma unroll
            for (int r = 0; r < 4; ++r)
                Pw[(quad * 4 + r) * 232 + mt * 16 + m16] = f2bf(s[mt][r] * inv[r]);

        f32x4 o[4];
        #pragma unroll
        for (int dt = 0; dt < 4; ++dt) o[dt] = z4;
        #pragma unroll
        for (int ks = 0; ks < 7; ++ks) {
            const bf16x8 a = *reinterpret_cast<const bf16x8*>(Pw + m16 * 232 + ks * 32 + quad * 8);
            #pragma unroll
            for (int dt = 0; dt < 4; ++dt) {
                const bf16x8 bf = *reinterpret_cast<const bf16x8*>(
                    Vs + (dt * 16 + m16) * 232 + ks * 32 + quad * 8);
                o[dt] = __builtin_amdgcn_mfma_f32_16x16x32_bf16(a, bf, o[dt], 0, 0, 0);
            }
        }
        #pragma unroll
        for (int r = 0; r < 4; ++r) {
            const int n = nt * 16 + quad * 4 + r;
            if (n < N_) {
                const int j = b * NP_ + n;
                #pragma unroll
                for (int dt = 0; dt < 4; ++dt) {
                    const int c = h * HD_ + dt * 16 + m16;
                    OT[(size_t)(j >> 4) * 8192 + (c >> 5) * 512
                       + ((c >> 3) & 3) * 128 + (j & 15) * 8 + (c & 7)] = f2bf(o[dt][r]);
                }
            }
        }
    }
}

extern "C" void kernel_launch(void* const* d_in, const int* in_sizes, int n_in,
                              void* d_out, int out_size, void* d_ws, size_t ws_size,
                              hipStream_t stream) {
    const float* x      = (const float*)d_in[0];
    const float* qkv_w  = (const float*)d_in[1];
    const float* qkv_b  = (const float*)d_in[2];
    const float* proj_w = (const float*)d_in[3];
    const float* proj_b = (const float*)d_in[4];
    const float* biases = (const float*)d_in[5];
    const int*   bidx   = (const int*)d_in[6];
    float* out = (float*)d_out;

    // ws layout (~92 MB; 103 MB proven safe):
    char* w = (char*)d_ws;
    u16* XT  = (u16*)w; w += (size_t)B_ * NP_ * DIM_ * 2;            // 29.4 MB frag-major (reused as OT)
    u16* qTw = (u16*)w; w += (size_t)B_ * HEADS_ * NP_ * HD_ * 2;    // 29.4 MB
    u16* vSw = (u16*)w; w += (size_t)B_ * HEADS_ * HD_ * NP_ * 2;    // 29.4 MB
    float* EB = (float*)w; w += (size_t)HEADS_ * NROW_ * NP_ * 4;    // 1.5 MB
    u16* wq  = (u16*)w; w += (size_t)3 * DIM_ * DIM_ * 2;            // 1.6 MB frag-major
    u16* wpj = (u16*)w;                                              // 0.5 MB frag-major
    u16* kTw = (u16*)d_out;                                          // kT parked in d_out

    cvt_w2<<<dim3(384, 2), 256, 0, stream>>>(qkv_w, wq, proj_w, wpj);
    cvt_xT<<<dim3(8, 4, B_), 256, 0, stream>>>(x, XT);
    mk_eb<<<dim3(NROW_, HEADS_), 256, 0, stream>>>(biases, bidx, EB);
    gemmJ<12><<<dim3(J_ / 128), 512, 0, stream>>>(XT, wq, qkv_b, qTw, kTw, vSw, nullptr);
    attn_mfma<<<dim3(B_, HEADS_), 512, 0, stream>>>(qTw, kTw, vSw, EB, XT);
    gemmJ<4><<<dim3(J_ / 128), 512, 0, stream>>>(XT, wpj, proj_b, nullptr, nullptr, nullptr, out);
}

// Round 10
// 261.846 us; speedup vs baseline: 1.2998x; 1.2998x over previous
//
#include <hip/hip_runtime.h>
#include <hip/hip_bf16.h>
#include <math.h>

#define B_     128
#define DIM_   512
#define HEADS_ 8
#define HD_    64
#define N_     196
#define NP_    224            // padded n (14 tiles of 16)
#define NROW_  208            // padded n rows (13 tiles of 16) for EB
#define SCALE_ 0.125f
#define BSTRIDE (DIM_ * N_)
#define J_     (B_ * NP_)     // 28672 GEMM columns (b*224+n)

typedef unsigned short u16;
typedef unsigned int   u32;
typedef __attribute__((ext_vector_type(8))) short bf16x8;   // 8 bf16 = 4 VGPRs
typedef __attribute__((ext_vector_type(4))) float f32x4;

__device__ __forceinline__ u16 f2bf(float f) {              // RNE fp32->bf16
    u32 u = __float_as_uint(f);
    return (u16)((u + 0x7fffu + ((u >> 16) & 1u)) >> 16);
}
__device__ __forceinline__ void gload_lds16(const u16* g, u16* l) {
    // async global->LDS, 16B/lane; LDS dest = wave-uniform base + lane*16
    __builtin_amdgcn_global_load_lds(
        (const __attribute__((address_space(1))) void*)g,
        (__attribute__((address_space(3))) void*)l, 16, 0, 0);
}

// ---------------------------------------------------------------------------
// Frag-major layout (r11, verified): FM[row/16][k/32][quad][m16][8 bf16].
// u16 addr(row,k) = (row>>4)*8192 + (k>>5)*512 + ((k>>3)&3)*128 + (row&15)*8
//                 + (k&7)        [K=512 fixed -> 16 kt slots]
// One MFMA fragment (16 rows x 8 k for 64 lanes) = 1 KB CONTIGUOUS.
// ---------------------------------------------------------------------------

// ---------------------------------------------------------------------------
// r15: FUSED prep kernel -- one launch replaces cvt_w2 + cvt_xT + mk_eb
// (independent work, block-range routed; saves 2 launch gaps and overlaps
// their memory traffic). Bodies are the r11/r13-verified ones, unchanged.
//   blocks [0,4096)            : cvt_xT  (ct=id&7, ntb=(id>>3)&3, b=id>>5)
//   blocks [4096,5760)         : mk_eb   (e: n=e%208, h=e/208)
//   blocks [5760,6144)         : cvt_w2 qkv  (chunk block 0..383)
//   blocks [6144,6272)         : cvt_w2 proj (chunk block 0..127)
// ---------------------------------------------------------------------------
__global__ __launch_bounds__(256) void prep(
    const float* __restrict__ x, u16* __restrict__ XT,
    const float* __restrict__ qw, u16* __restrict__ qd,
    const float* __restrict__ pw, u16* __restrict__ pd,
    const float* __restrict__ biases, const int* __restrict__ bidx,
    float* __restrict__ EB)
{
    const int id = blockIdx.x;
    const int t = threadIdx.x;
    if (id < 4096) {                     // ---- cvt_xT ----
        __shared__ float tile[64][65];
        const int jj = t & 63, ii = t >> 6;
        const int ct = id & 7, ntb = (id >> 3) & 3, b = id >> 5;
        const float* xb = x + ((size_t)b * DIM_ + ct * 64) * N_;
        const int n0 = ntb * 64;
        #pragma unroll
        for (int s = 0; s < 16; ++s) {
            const int i = ii + s * 4;
            const int n = n0 + jj;
            tile[i][jj] = (n < N_) ? xb[(size_t)i * N_ + n] : 0.f;
        }
        __syncthreads();
        const int lo = t & 15, hi = t >> 4;
        const int c8 = hi & 7, ng = hi >> 3;
        #pragma unroll
        for (int s = 0; s < 2; ++s) {
            const int n_loc = (s * 2 + ng) * 16 + lo;
            const int nn = n0 + n_loc;
            if (nn < N_) {
                const int j = b * NP_ + nn;        // j&15 == lo
                const int c0 = ct * 64 + c8 * 8;
                u16 vv[8];
                #pragma unroll
                for (int e = 0; e < 8; ++e) vv[e] = f2bf(tile[c8 * 8 + e][n_loc]);
                uint4 o;
                o.x = (u32)vv[0] | ((u32)vv[1] << 16);
                o.y = (u32)vv[2] | ((u32)vv[3] << 16);
                o.z = (u32)vv[4] | ((u32)vv[5] << 16);
                o.w = (u32)vv[6] | ((u32)vv[7] << 16);
                *reinterpret_cast<uint4*>(XT + (size_t)(j >> 4) * 8192
                    + (c0 >> 5) * 512 + ((c0 >> 3) & 3) * 128 + (j & 15) * 8) = o;
            }
        }
    } else if (id < 5760) {              // ---- mk_eb ----
        const int e = id - 4096;
        const int n = e % NROW_, h = e / NROW_;
        const int m = t;
        if (m < NP_) {
            float v = 0.f;
            if (n < N_ && m < N_) v = __expf(biases[h * N_ + bidx[n * N_ + m]]);
            EB[((size_t)h * NROW_ + n) * NP_ + m] = v;
        }
    } else {                             // ---- cvt_w2 ----
        const bool pj = id >= 6144;
        const int cb = id - (pj ? 6144 : 5760);
        const float* src = pj ? pw : qw;
        u16* dst = pj ? pd : qd;
        const int nch = pj ? (DIM_ * DIM_ / 8) : (3 * DIM_ * DIM_ / 8);
        const int c = cb * 256 + t;
        if (c < nch) {
            const int m16 = c & 15, q = (c >> 4) & 3, kb = (c >> 6) & 15, mb = c >> 10;
            const float* s = src + (size_t)(mb * 16 + m16) * DIM_ + kb * 32 + q * 8;
            const float4 v0 = reinterpret_cast<const float4*>(s)[0];
            const float4 v1 = reinterpret_cast<const float4*>(s)[1];
            uint4 o;
            o.x = (u32)f2bf(v0.x) | ((u32)f2bf(v0.y) << 16);
            o.y = (u32)f2bf(v0.z) | ((u32)f2bf(v0.w) << 16);
            o.z = (u32)f2bf(v1.x) | ((u32)f2bf(v1.y) << 16);
            o.w = (u32)f2bf(v1.z) | ((u32)f2bf(v1.w) << 16);
            reinterpret_cast<uint4*>(dst)[c] = o;
        }
    }
}

// ---------------------------------------------------------------------------
// r15 GEMM: r8's PROVEN 2-phase 128x128 4-wave template, BK 32 -> 64 with
// frag-major LDS. Why: five structures (r8/r9/r11/r12/r14) all pinned at
// 78-122us = the m233 2-phase ceiling (~600 TF); aggregate floors (LDS 11us,
// L2 5us, HBM 19us, MFMA 22us) rule out every pipe -- residual is the
// per-iteration drain of prefetch loads with only ~200cy cover. BK=64:
// barrier-drain events 16 -> 8, prefetch cover ~400cy (16 ds_read + 32 MFMA
// between issue and drain). Frag-major staging: src AND dst contiguous 16B
// chunks (8 gload_lds/thread/tile), ds_read_b128 frags conflict-free by
// construction (r14: 0 conflicts). Sync structure IDENTICAL to r8 (verified
// race-free): [syncthreads drain -> issue next-tile loads -> compute].
// LDS 2x(16+16) KB = 64 KB -> 2 blocks/CU. Epilogue + wave map = r11
// (verified): 4 waves, 64x64/wave, acc 4x4, j0=jt*128.
// XCD swizzle (verified r8: FETCH 87->34MB): mt-fastest, bijective, NWG%8==0.
// ---------------------------------------------------------------------------
template<bool QKV>
__global__ __launch_bounds__(256) void gemmF(
    const u16* __restrict__ Bt, const u16* __restrict__ W,
    const float* __restrict__ bias,
    u16* __restrict__ o_q, u16* __restrict__ o_k, u16* __restrict__ o_v,
    float* __restrict__ o_f)
{
    __shared__ u16 As[2][8192];         // 2 x 16 KB (128 rows x 64 k, frag-major)
    __shared__ u16 Bs[2][8192];         // 2 x 16 KB
    const int t = threadIdx.x;
    const int wave = t >> 6, lane = t & 63;
    const int m16 = lane & 15, quad = lane >> 4;

    constexpr int MT  = QKV ? 12 : 4;
    constexpr int NWG = (J_ / 128) * MT;
    const int bid = blockIdx.x;
    const int swz = (bid & 7) * (NWG / 8) + (bid >> 3);   // bijective XCD swizzle
    const int mt = swz % MT;                               // mt fastest
    const int jt = swz / MT;
    const int m0 = mt * 128, j0 = jt * 128;
    const int wy = wave >> 1, wx = wave & 1;     // wave tile: rows wy*64, cols wx*64

    // staging: per tile, A and B each = 16 KB = 1024 x 16B chunks; thread does
    // 4 chunks each (c-loop). chunk g = c*256+t: frag-row f=g>>7, slot s=(g>>6)&1,
    // lane-chunk ch=g&63. src frag-major; dst LDS linear g*8 u16 (wave-uniform
    // base + lane*16B per call).
    const u16* gAb = W  + (size_t)(mt * 8) * 8192;
    const u16* gBb = Bt + (size_t)(jt * 8) * 8192;

    // frag read: frag-row fr, slot ks -> (fr*2+ks)*512 + quad*128 + m16*8
    const int roff = quad * 128 + m16 * 8;

    f32x4 acc[4][4];
    const f32x4 z4 = {0.f, 0.f, 0.f, 0.f};
    #pragma unroll
    for (int fi = 0; fi < 4; ++fi)
        #pragma unroll
        for (int fj = 0; fj < 4; ++fj) acc[fi][fj] = z4;

    // prologue: stage tile 0 into buf 0
    #pragma unroll
    for (int c = 0; c < 4; ++c) {
        const int g = c * 256 + t;
        const int f = g >> 7, s = (g >> 6) & 1, ch = g & 63;
        gload_lds16(gAb + (size_t)f * 8192 + s * 512 + ch * 8, As[0] + g * 8);
        gload_lds16(gBb + (size_t)f * 8192 + s * 512 + ch * 8, Bs[0] + g * 8);
    }
    for (int kt = 0; kt < 8; ++kt) {             // 8 K-tiles of 64
        const int cur = kt & 1;
        __syncthreads();      // vmcnt(0)+lgkmcnt(0) drain: tile-kt staged &
                              // visible; all waves done reading buf[cur^1]
        if (kt < 7) {         // prefetch tile kt+1 (cover = this tile's compute)
            #pragma unroll
            for (int c = 0; c < 4; ++c) {
                const int g = c * 256 + t;
                const int f = g >> 7, s = (g >> 6) & 1, ch = g & 63;
                gload_lds16(gAb + (size_t)f * 8192 + ((kt + 1) * 2 + s) * 512 + ch * 8, As[cur ^ 1] + g * 8);
                gload_lds16(gBb + (size_t)f * 8192 + ((kt + 1) * 2 + s) * 512 + ch * 8, Bs[cur ^ 1] + g * 8);
            }
        }
        #pragma unroll
        for (int ks = 0; ks < 2; ++ks) {
            bf16x8 af[4], bf[4];
            #pragma unroll
            for (int fi = 0; fi < 4; ++fi)
                af[fi] = *reinterpret_cast<const bf16x8*>(As[cur] + ((wy * 4 + fi) * 2 + ks) * 512 + roff);
            #pragma unroll
            for (int fj = 0; fj < 4; ++fj)
                bf[fj] = *reinterpret_cast<const bf16x8*>(Bs[cur] + ((wx * 4 + fj) * 2 + ks) * 512 + roff);
            #pragma unroll
            for (int fi = 0; fi < 4; ++fi)
                #pragma unroll
                for (int fj = 0; fj < 4; ++fj)
                    acc[fi][fj] = __builtin_amdgcn_mfma_f32_16x16x32_bf16(af[fi], bf[fj], acc[fi][fj], 0, 0, 0);
        }
    }

    // ---- epilogue (r11-verified) ----
    const int mbase = m0 + wy * 64;              // 64-aligned -> part,h wave-uniform
    float bb[4][4];
    #pragma unroll
    for (int fi = 0; fi < 4; ++fi)
        #pragma unroll
        for (int r = 0; r < 4; ++r) bb[fi][r] = bias[mbase + fi * 16 + quad * 4 + r];

    if (QKV) {
        const int part = mbase >> 9;             // 0=q 1=k 2=v
        const int h = (mbase & 511) >> 6;
        #pragma unroll
        for (int fj = 0; fj < 4; ++fj) {
            const int j = j0 + wx * 64 + fj * 16 + m16;
            const u32 b = (u32)j / 224u;
            const int n = j - (int)b * 224;
            if (part < 2) {                      // q,k -> [b][h][n][64], 8B packed
                u16* base = (part == 0 ? o_q : o_k) + (((size_t)b * HEADS_ + h) * NP_ + n) * HD_;
                #pragma unroll
                for (int fi = 0; fi < 4; ++fi) {
                    const int d0 = fi * 16 + quad * 4;
                    uint2 pk;
                    pk.x = (u32)f2bf(acc[fi][fj][0] + bb[fi][0]) | ((u32)f2bf(acc[fi][fj][1] + bb[fi][1]) << 16);
                    pk.y = (u32)f2bf(acc[fi][fj][2] + bb[fi][2]) | ((u32)f2bf(acc[fi][fj][3] + bb[fi][3]) << 16);
                    *reinterpret_cast<uint2*>(base + d0) = pk;
                }
            } else {                             // v -> [b][h][d][224], 2B stores
                u16* vb = o_v + (((size_t)b * HEADS_ + h) * HD_) * NP_ + n;
                #pragma unroll
                for (int fi = 0; fi < 4; ++fi) {
                    const int d0 = fi * 16 + quad * 4;
                    #pragma unroll
                    for (int r = 0; r < 4; ++r)
                        vb[(size_t)(d0 + r) * NP_] = f2bf(acc[fi][fj][r] + bb[fi][r]);
                }
            }
        }
    } else {                                     // proj: fp32 out[b][512][196]
        #pragma unroll
        for (int fj = 0; fj < 4; ++fj) {
            const int j = j0 + wx * 64 + fj * 16 + m16;
            const u32 b = (u32)j / 224u;
            const int n = j - (int)b * 224;
            if (n < N_) {
                float* ob = o_f + (size_t)b * BSTRIDE + n;
                #pragma unroll
                for (int fi = 0; fi < 4; ++fi) {
                    const int r0 = mbase + fi * 16 + quad * 4;
                    #pragma unroll
                    for (int r = 0; r < 4; ++r)
                        ob[(size_t)(r0 + r) * N_] = acc[fi][fj][r] + bb[fi][r];
                }
            }
        }
    }
}

// ---------------------------------------------------------------------------
// MFMA attention per (b,h), 8 waves (512 thr). K and V staged in LDS once
// per block (verified r6 structure; r11: OT store frag-major, verified).
//   Ks[224][64] u16, chunk-XOR swizzled; Vs[64][232] row-padded;
//   P[8][16*232] per-wave. LDS 117.8 KB -> 1 block/CU.
// mx over all 14 mtiles incl. pads, EB=0 masks pad m; OT stores guarded n<196.
// ---------------------------------------------------------------------------
__global__ __launch_bounds__(512) void attn_mfma(
    const u16* __restrict__ qT, const u16* __restrict__ kT,
    const u16* __restrict__ vS, const float* __restrict__ EB,
    u16* __restrict__ OT)
{
    __shared__ u16 Ks[224 * 64];        // 28.7 KB, chunk-XOR swizzled
    __shared__ u16 Vs[64 * 232];        // 29.7 KB, row-padded
    __shared__ u16 P[8][16 * 232];      // 59.4 KB
    const int t = threadIdx.x;
    const int wave = t >> 6, lane = t & 63;
    const int m16 = lane & 15, quad = lane >> 4;
    const int b = blockIdx.x, h = blockIdx.y;
    const u16* qTb = qT + ((size_t)b * HEADS_ + h) * (NP_ * HD_);
    const u16* kTb = kT + ((size_t)b * HEADS_ + h) * (NP_ * HD_);
    const u16* vb  = vS + ((size_t)b * HEADS_ + h) * (HD_ * NP_);
    const float* ebh = EB + (size_t)h * NROW_ * NP_;
    u16* Pw = P[wave];
    const f32x4 z4 = {0.f, 0.f, 0.f, 0.f};

    // ---- stage K: 224 rows x 8 chunks(16B) = 1792 chunks over 512 thr ----
    #pragma unroll
    for (int i = 0; i < 4; ++i) {
        const int c = t + i * 512;
        if (c < 1792) {
            const int row = c >> 3, ch = c & 7;
            const bf16x8 d = *reinterpret_cast<const bf16x8*>(kTb + row * HD_ + ch * 8);
            *reinterpret_cast<bf16x8*>(Ks + row * 64 + ((ch ^ (row & 7)) * 8)) = d;
        }
    }
    // ---- stage V: 64 rows x 28 chunks(16B) = 1792 chunks, repack to 232 ----
    #pragma unroll
    for (int i = 0; i < 4; ++i) {
        const int c = t + i * 512;
        if (c < 1792) {
            const u32 row = (u32)c / 28u;
            const int ch = c - (int)row * 28;
            const bf16x8 d = *reinterpret_cast<const bf16x8*>(vb + (size_t)row * NP_ + ch * 8);
            *reinterpret_cast<bf16x8*>(Vs + row * 232 + ch * 8) = d;
        }
    }
    __syncthreads();

    for (int nt = wave; nt < 13; nt += 8) {
        f32x4 s[14];
        #pragma unroll
        for (int mt = 0; mt < 14; ++mt) s[mt] = z4;
        #pragma unroll
        for (int ks = 0; ks < 2; ++ks) {
            const bf16x8 a = *reinterpret_cast<const bf16x8*>(
                qTb + (size_t)(nt * 16 + m16) * HD_ + ks * 32 + quad * 8);
            const int ch = ((ks * 4 + quad) ^ (m16 & 7)) * 8;   // K swizzle inverse
            #pragma unroll
            for (int mtile = 0; mtile < 14; ++mtile) {
                const bf16x8 bf = *reinterpret_cast<const bf16x8*>(
                    Ks + (mtile * 16 + m16) * 64 + ch);
                s[mtile] = __builtin_amdgcn_mfma_f32_16x16x32_bf16(a, bf, s[mtile], 0, 0, 0);
            }
        }
        float mx[4] = {-INFINITY, -INFINITY, -INFINITY, -INFINITY};
        #pragma unroll
        for (int mt = 0; mt < 14; ++mt)
            #pragma unroll
            for (int r = 0; r < 4; ++r) mx[r] = fmaxf(mx[r], s[mt][r]);
        #pragma unroll
        for (int off = 1; off < 16; off <<= 1)
            #pragma unroll
            for (int r = 0; r < 4; ++r) mx[r] = fmaxf(mx[r], __shfl_xor(mx[r], off, 64));
        #pragma unroll
        for (int r = 0; r < 4; ++r) mx[r] *= SCALE_;

        const float* ebn = ebh + (size_t)(nt * 16 + quad * 4) * NP_ + m16;
        float sum[4] = {0.f, 0.f, 0.f, 0.f};
        #pragma unroll
        for (int mt = 0; mt < 14; ++mt) {
            #pragma unroll
            for (int r = 0; r < 4; ++r) {
                const float e = __expf(fmaf(s[mt][r], SCALE_, -mx[r])) * ebn[(size_t)r * NP_ + mt * 16];
                s[mt][r] = e;
                sum[r] += e;
            }
        }
        #pragma unroll
        for (int off = 1; off < 16; off <<= 1)
            #pragma unroll
            for (int r = 0; r < 4; ++r) sum[r] += __shfl_xor(sum[r], off, 64);
        float inv[4];
        #pragma unroll
        for (int r = 0; r < 4; ++r) inv[r] = 1.f / sum[r];

        #pragma unroll
        for (int mt = 0; mt < 14; ++mt)
            #pragma unroll
            for (int r = 0; r < 4; ++r)
                Pw[(quad * 4 + r) * 232 + mt * 16 + m16] = f2bf(s[mt][r] * inv[r]);

        f32x4 o[4];
        #pragma unroll
        for (int dt = 0; dt < 4; ++dt) o[dt] = z4;
        #pragma unroll
        for (int ks = 0; ks < 7; ++ks) {
            const bf16x8 a = *reinterpret_cast<const bf16x8*>(Pw + m16 * 232 + ks * 32 + quad * 8);
            #pragma unroll
            for (int dt = 0; dt < 4; ++dt) {
                const bf16x8 bf = *reinterpret_cast<const bf16x8*>(
                    Vs + (dt * 16 + m16) * 232 + ks * 32 + quad * 8);
                o[dt] = __builtin_amdgcn_mfma_f32_16x16x32_bf16(a, bf, o[dt], 0, 0, 0);
            }
        }
        #pragma unroll
        for (int r = 0; r < 4; ++r) {
            const int n = nt * 16 + quad * 4 + r;
            if (n < N_) {
                const int j = b * NP_ + n;
                #pragma unroll
                for (int dt = 0; dt < 4; ++dt) {
                    const int c = h * HD_ + dt * 16 + m16;
                    OT[(size_t)(j >> 4) * 8192 + (c >> 5) * 512
                       + ((c >> 3) & 3) * 128 + (j & 15) * 8 + (c & 7)] = f2bf(o[dt][r]);
                }
            }
        }
    }
}

extern "C" void kernel_launch(void* const* d_in, const int* in_sizes, int n_in,
                              void* d_out, int out_size, void* d_ws, size_t ws_size,
                              hipStream_t stream) {
    const float* x      = (const float*)d_in[0];
    const float* qkv_w  = (const float*)d_in[1];
    const float* qkv_b  = (const float*)d_in[2];
    const float* proj_w = (const float*)d_in[3];
    const float* proj_b = (const float*)d_in[4];
    const float* biases = (const float*)d_in[5];
    const int*   bidx   = (const int*)d_in[6];
    float* out = (float*)d_out;

    // ws layout (~92 MB; 103 MB proven safe):
    char* w = (char*)d_ws;
    u16* XT  = (u16*)w; w += (size_t)B_ * NP_ * DIM_ * 2;            // 29.4 MB frag-major (reused as OT)
    u16* qTw = (u16*)w; w += (size_t)B_ * HEADS_ * NP_ * HD_ * 2;    // 29.4 MB
    u16* vSw = (u16*)w; w += (size_t)B_ * HEADS_ * HD_ * NP_ * 2;    // 29.4 MB
    float* EB = (float*)w; w += (size_t)HEADS_ * NROW_ * NP_ * 4;    // 1.5 MB
    u16* wq  = (u16*)w; w += (size_t)3 * DIM_ * DIM_ * 2;            // 1.6 MB frag-major
    u16* wpj = (u16*)w;                                              // 0.5 MB frag-major
    u16* kTw = (u16*)d_out;                                          // kT parked in d_out

    prep<<<dim3(6272), 256, 0, stream>>>(x, XT, qkv_w, wq, proj_w, wpj, biases, bidx, EB);
    gemmF<true><<<dim3((J_ / 128) * 12), 256, 0, stream>>>(XT, wq, qkv_b, qTw, kTw, vSw, nullptr);
    attn_mfma<<<dim3(B_, HEADS_), 512, 0, stream>>>(qTw, kTw, vSw, EB, XT);
    gemmF<false><<<dim3((J_ / 128) * 4), 256, 0, stream>>>(XT, wpj, proj_b, nullptr, nullptr, nullptr, out);
}